// Round 1
// baseline (236.245 us; speedup 1.0000x reference)
//
#include <hip/hip_runtime.h>
#include <stdint.h>

typedef unsigned short u16;
typedef __attribute__((ext_vector_type(8))) short bf16x8;
typedef __attribute__((ext_vector_type(4))) float f32x4;

// ---- constants (problem shape) ----
#define Bsz   8192
#define Vv    4000
#define Vpad  4096
#define Ee    256
#define Uu    256
#define INd   512
#define G3    768   // 3*U

__device__ __forceinline__ u16 f2bf(float f) {
    union { float f; uint32_t i; } v; v.f = f;
    uint32_t x = v.i;
    return (u16)((x + 0x7fffu + ((x >> 16) & 1u)) >> 16);  // RNE
}

// async global->LDS, 16B per lane (dest = wave-uniform base + lane*16)
__device__ __forceinline__ void gload16(const u16* g, u16* l) {
    __builtin_amdgcn_global_load_lds(
        (const __attribute__((address_space(1))) unsigned int*)g,
        (__attribute__((address_space(3))) unsigned int*)l, 16, 0, 0);
}

// ---- prep: weight transposes (f32 [K][N] -> bf16 [Nout][K]), fc1 cast, fused bias ----
// blocks: w1 24*16=384 | fc1 cast 64 | fc2 128*8=1024 | bias 16  -> 1488 blocks
__global__ __launch_bounds__(256) void prep_all(
    const float* __restrict__ w1,  u16* __restrict__ w1t,
    const float* __restrict__ fc1, u16* __restrict__ fc1c,
    const float* __restrict__ fc2, u16* __restrict__ fc2t,
    const float* __restrict__ fc1b, const float* __restrict__ fc2b,
    float* __restrict__ bfused)
{
    __shared__ float t[32][33];
    int b = blockIdx.x;
    if (b >= 1472) {                        // fused bias: b[n] = fc1_b @ fc2[:,n] + fc2_b[n]
        int nl = (b - 1472) * 256 + threadIdx.x;
        if (nl < Vv) {
            float s = fc2b[nl];
            for (int k = 0; k < Uu; k++)
                s += fc1b[k] * fc2[(size_t)k * Vv + nl];
            bfused[nl] = s;
        }
        return;
    }
    if (b >= 384 && b < 448) {              // fc1 straight cast (natural [j][ko] layout)
        int i = (b - 384) * 1024 + threadIdx.x * 4;
        float4 v = *(const float4*)(fc1 + i);
        __align__(8) u16 o[4] = {f2bf(v.x), f2bf(v.y), f2bf(v.z), f2bf(v.w)};
        *(uint2*)&fc1c[i] = *(const uint2*)o;
        return;
    }
    const float* in; u16* out; int K, N, bx, by;
    if (b < 384) { in = w1;  out = w1t;  K = 512; N = 768; bx = b % 24;  by = b / 24; }
    else { b -= 448; in = fc2; out = fc2t; K = 256; N = Vv; bx = b % 128; by = b / 128; }
    int n0 = bx * 32, k0 = by * 32;
    int c = threadIdx.x & 31, r = threadIdx.x >> 5;   // 8 rows per phase
    int n = n0 + c;
    #pragma unroll
    for (int i = 0; i < 32; i += 8)
        t[r + i][c] = (n < N) ? in[(size_t)(k0 + r + i) * N + n] : 0.f;
    __syncthreads();
    #pragma unroll
    for (int i = 0; i < 32; i += 8)
        out[(size_t)(n0 + r + i) * K + k0 + c] = f2bf(t[c][r + i]);
}

// ---- fused gather + GEMM1 + GRU cell (h0=0): tile 64 batch x 64 h-cols x 3 gates ----
// Single-barrier pipelined: per iter {sync; issue B(t+1)+stage A(t+1)+load a(t+2); compute t}.
// All staging has a full compute phase to land before the next barrier drains it.
__global__ __launch_bounds__(256) void gru_fused(
    const int* __restrict__ tokens, const float* __restrict__ features,
    const float* __restrict__ emb,  const u16* __restrict__ BT,   // w1t [768 x 512] bf16
    const float* __restrict__ gb,   // gru_bias [2 x 768] f32
    u16* __restrict__ h,            // [B x 256] bf16 (ws)
    float* __restrict__ state)      // [B x 256] f32 (output 1)
{
    __shared__ __align__(16) u16 As[2][64 * 32];
    __shared__ __align__(16) u16 Bs[2][3][64 * 32];
    __shared__ int tok[64];

    int tid = threadIdx.x;
    // chunked XCD swizzle: 512 blocks -> 64 consecutive per XCD (features rows shared by
    // the 4 n-tiles of the same m-tile stay in one XCD's L2)
    int id  = blockIdx.y * gridDim.x + blockIdx.x;
    int sid = (id & 7) * 64 + (id >> 3);
    int m0  = (sid >> 2) * 64;
    int n0  = (sid & 3) * 64;
    if (tid < 64) tok[tid] = tokens[m0 + tid];

    int wid = tid >> 6, lane = tid & 63, quad = lane >> 4, l16 = lane & 15;
    int wm = wid * 16;             // wave owns 16 rows x 64 cols x 3 gates

    f32x4 acc[3][4] = {};

    int r  = tid >> 2;             // 0..63 row
    int kc = (tid & 3) * 8;        // k-chunk within 32
    const u16* bg = BT + (size_t)(n0 + r) * INd + kc;
    const float* fsrc = features + (size_t)(m0 + r) * Ee + kc;

    // prologue: B(0) -> Bs[0]; convert A(0) -> As[0]; preload a-regs for k=32
    #pragma unroll
    for (int g = 0; g < 3; g++)
        gload16(bg + (size_t)g * 256 * INd, &Bs[0][g][tid * 8]);
    float4 a = *(const float4*)fsrc;            // k=0 (< Ee)
    float4 c = *(const float4*)(fsrc + 4);
    {
        u16 o[8] = {f2bf(a.x), f2bf(a.y), f2bf(a.z), f2bf(a.w),
                    f2bf(c.x), f2bf(c.y), f2bf(c.z), f2bf(c.w)};
        *(uint4*)&As[0][tid * 8] = *(const uint4*)o;
    }
    a = *(const float4*)(fsrc + 32);            // k=32 (< Ee)
    c = *(const float4*)(fsrc + 36);

    int cur = 0;
    for (int k0 = 0; k0 < INd; k0 += 32) {
        __syncthreads();   // drains B(k0)/a-regs; publishes As/Bs[cur] and tok[]
        int k1 = k0 + 32;
        if (k1 < INd) {
            // issue next-tile B loads (land during compute)
            #pragma unroll
            for (int g = 0; g < 3; g++)
                gload16(bg + (size_t)g * 256 * INd + k1, &Bs[cur ^ 1][g][tid * 8]);
            // stage A(k1) from regs loaded last iteration
            u16 o[8] = {f2bf(a.x), f2bf(a.y), f2bf(a.z), f2bf(a.w),
                        f2bf(c.x), f2bf(c.y), f2bf(c.z), f2bf(c.w)};
            *(uint4*)&As[cur ^ 1][tid * 8] = *(const uint4*)o;
            int k2 = k0 + 64;
            if (k2 < INd) {
                const float* src = (k2 < Ee) ? (fsrc + k2)
                                 : (emb + (size_t)tok[r] * Ee + (k2 - Ee) + kc);
                a = *(const float4*)src;
                c = *(const float4*)(src + 4);
            }
        }
        // compute tile t from As[cur], Bs[cur]
        bf16x8 af = *(const bf16x8*)&As[cur][(wm + l16) * 32 + quad * 8];
        #pragma unroll
        for (int g = 0; g < 3; g++)
            #pragma unroll
            for (int j = 0; j < 4; j++) {
                bf16x8 bfv = *(const bf16x8*)&Bs[cur][g][(j * 16 + l16) * 32 + quad * 8];
                acc[g][j] = __builtin_amdgcn_mfma_f32_16x16x32_bf16(af, bfv, acc[g][j], 0, 0, 0);
            }
        cur ^= 1;
    }

    // C/D layout: col = l16, row = quad*4 + r (verified)
    #pragma unroll
    for (int j = 0; j < 4; j++) {
        int jj = n0 + j * 16 + l16;
        float bz  = gb[jj]          + gb[G3 + jj];
        float br  = gb[Uu + jj]     + gb[G3 + Uu + jj];
        float b0n = gb[2 * Uu + jj];
        float b1n = gb[G3 + 2 * Uu + jj];
        #pragma unroll
        for (int rr = 0; rr < 4; rr++) {
            int b = m0 + wm + quad * 4 + rr;
            float z  = 1.f / (1.f + __expf(-(acc[0][j][rr] + bz)));
            float rg = 1.f / (1.f + __expf(-(acc[1][j][rr] + br)));
            float n  = tanhf(acc[2][j][rr] + b0n + rg * b1n);
            float hv = (1.f - z) * n;
            h[(size_t)b * Uu + jj] = f2bf(hv);
            state[(size_t)b * Uu + jj] = hv;
        }
    }
}

// ---- m97-style GEMM: C[M x N] = A[M x K](bf16) @ BT[Nb x K]^T(bf16) (+ bias) ----
// 256 thr / 4 waves, BK=32, unpadded LDS, global_load_lds w=16
template<int BMt, int BNt, bool OUT_BF16, bool SWZ, bool HAS_BIAS>
__global__ __launch_bounds__(256) void gemm_bt(
    const u16* __restrict__ A, const u16* __restrict__ BT,
    const float* __restrict__ bias, void* __restrict__ Cout,
    int N, int K)   // N = real out cols (epilogue-guarded); grid covers padded cols
{
    constexpr int NW_N  = (BNt == 128) ? 2 : 1;   // waves along n
    constexpr int NW_M  = 4 / NW_N;               // waves along m
    constexpr int WROWS = BMt / NW_M;             // rows per wave
    constexpr int MI    = WROWS / 16;

    __shared__ __align__(16) u16 As[BMt * 32];
    __shared__ __align__(16) u16 Bs[BNt * 32];

    int tid = threadIdx.x;
    int bx  = blockIdx.x, by = blockIdx.y;
    if (SWZ) {   // chunked XCD swizzle: each XCD owns nwg/8 consecutive tiles
        int nx  = gridDim.x;
        int nwg = nx * gridDim.y;                 // must be % 8 == 0
        int id  = by * nx + bx;
        int sid = (id & 7) * (nwg >> 3) + (id >> 3);
        bx = sid % nx; by = sid / nx;
    }
    int m0   = by * BMt;
    int n0   = bx * BNt;
    int wid  = tid >> 6, lane = tid & 63, quad = lane >> 4, l16 = lane & 15;
    int wm   = (wid / NW_N) * WROWS;
    int wn   = (wid % NW_N) * 64;

    f32x4 acc[MI][4] = {};

    const u16* ag = A  + (size_t)(m0 + (tid >> 2)) * K + (tid & 3) * 8;
    const u16* bg = BT + (size_t)(n0 + (tid >> 2)) * K + (tid & 3) * 8;
    u16* lA = &As[tid * 8];
    u16* lB = &Bs[tid * 8];

    for (int k0 = 0; k0 < K; k0 += 32) {
        __syncthreads();
        #pragma unroll
        for (int s = 0; s < BMt / 64; s++)
            gload16(ag + (size_t)s * 64 * K + k0, lA + s * 64 * 32);
        #pragma unroll
        for (int s = 0; s < BNt / 64; s++)
            gload16(bg + (size_t)s * 64 * K + k0, lB + s * 64 * 32);
        __syncthreads();

        bf16x8 af[MI], bf[4];
        #pragma unroll
        for (int i = 0; i < MI; i++)
            af[i] = *(const bf16x8*)&As[(wm + i * 16 + l16) * 32 + quad * 8];
        #pragma unroll
        for (int j = 0; j < 4; j++)
            bf[j] = *(const bf16x8*)&Bs[(wn + j * 16 + l16) * 32 + quad * 8];
        #pragma unroll
        for (int i = 0; i < MI; i++)
            #pragma unroll
            for (int j = 0; j < 4; j++)
                acc[i][j] = __builtin_amdgcn_mfma_f32_16x16x32_bf16(af[i], bf[j], acc[i][j], 0, 0, 0);
    }

    // C/D layout: col = l16, row = quad*4 + r (verified)
    #pragma unroll
    for (int i = 0; i < MI; i++)
    #pragma unroll
    for (int j = 0; j < 4; j++) {
        int gn = n0 + wn + j * 16 + l16;
        if (gn >= N) continue;
        float bv = HAS_BIAS ? bias[gn] : 0.f;
        #pragma unroll
        for (int r = 0; r < 4; r++) {
            int gm = m0 + wm + i * 16 + quad * 4 + r;
            float v = acc[i][j][r] + bv;
            if (OUT_BF16) ((u16*)Cout)[(size_t)gm * N + gn] = f2bf(v);
            else          ((float*)Cout)[(size_t)gm * N + gn] = v;
        }
    }
}

extern "C" void kernel_launch(void* const* d_in, const int* in_sizes, int n_in,
                              void* d_out, int out_size, void* d_ws, size_t ws_size,
                              hipStream_t stream)
{
    const int*   tokens   = (const int*)d_in[0];
    const float* features = (const float*)d_in[1];
    // d_in[2] = hidden (unused: reference GRU starts from zeros)
    const float* emb      = (const float*)d_in[3];
    const float* w1       = (const float*)d_in[4];   // [512 x 768]
    // d_in[5] = gru_rkernel (unused: h0 = 0)
    const float* gbias    = (const float*)d_in[6];   // [2 x 768]
    const float* fc1w     = (const float*)d_in[7];   // [256 x 256]
    const float* fc1b     = (const float*)d_in[8];
    const float* fc2w     = (const float*)d_in[9];   // [256 x 4000]
    const float* fc2b     = (const float*)d_in[10];

    float* logits = (float*)d_out;                       // [8192 x 4000] f32
    float* state  = logits + (size_t)Bsz * Vv;           // [8192 x 256] f32

    char* ws = (char*)d_ws;
    u16*   w1t    = (u16*)(ws);                 //   786,432 B : [768 x 512]
    u16*   fc1c   = (u16*)(ws +   786432);      //   131,072 B : [256 x 256] (cast, no transpose)
    u16*   fc2t   = (u16*)(ws +   917504);      // 2,097,152 B : [4096 x 256] (pad zeroed)
    u16*   Wt     = (u16*)(ws +  3014656);      // 2,097,152 B : [4096 x 256] = (fc1@fc2)^T
    u16*   h      = (u16*)(ws +  5111808);      // 4,194,304 B : [8192 x 256]
    float* bfused = (float*)(ws + 9306112);     //    16,000 B : [4000]
    // total ws use: 9,322,112 B

    // prep: transposes (f32 -> bf16, k-contiguous), fc1 cast, fused bias
    prep_all<<<dim3(1488), 256, 0, stream>>>(w1, w1t, fc1w, fc1c, fc2w, fc2t,
                                             fc1b, fc2b, bfused);

    // Wt[nl][j] = sum_ko fc2t[nl][ko] * fc1[j][ko]  -> collapsed fc1+fc2 weight, bf16
    gemm_bt<64, 64, true, false, false><<<dim3(Uu / 64, Vpad / 64), 256, 0, stream>>>(
        fc2t, fc1c, nullptr, (void*)Wt, Uu, Uu);

    // fused gather + gx-GEMM + GRU -> h (bf16) and state (f32 out)
    gru_fused<<<dim3(Uu / 64, Bsz / 64), 256, 0, stream>>>(
        tokens, features, emb, w1t, gbias, h, state);

    // logits = h @ W + bfused (f32 out), padded col grid, guarded epilogue, XCD-swizzled
    gemm_bt<128, 128, false, true, true><<<dim3(Vpad / 128, Bsz / 128), 256, 0, stream>>>(
        h, Wt, bfused, (void*)logits, Vv, Uu);
}

// Round 2
// 220.034 us; speedup vs baseline: 1.0737x; 1.0737x over previous
//
#include <hip/hip_runtime.h>
#include <stdint.h>

typedef unsigned short u16;
typedef __attribute__((ext_vector_type(8))) short bf16x8;
typedef __attribute__((ext_vector_type(4))) float f32x4;

// ---- constants (problem shape) ----
#define Bsz   8192
#define Vv    4000
#define Vpad  4096
#define Ee    256
#define Uu    256
#define INd   512
#define G3    768   // 3*U

__device__ __forceinline__ u16 f2bf(float f) {
    union { float f; uint32_t i; } v; v.f = f;
    uint32_t x = v.i;
    return (u16)((x + 0x7fffu + ((x >> 16) & 1u)) >> 16);  // RNE
}

// async global->LDS, 16B per lane (dest = wave-uniform base + lane*16)
__device__ __forceinline__ void gload16(const u16* g, u16* l) {
    __builtin_amdgcn_global_load_lds(
        (const __attribute__((address_space(1))) unsigned int*)g,
        (__attribute__((address_space(3))) unsigned int*)l, 16, 0, 0);
}

// ---- prep: weight transposes (f32 [K][N] -> bf16 [Nout][K]), fc1 cast, fused bias ----
// blocks: w1 24*16=384 | fc1 cast 64 | fc2 128*8=1024 | bias 64  -> 1536 blocks
__global__ __launch_bounds__(256) void prep_all(
    const float* __restrict__ w1,  u16* __restrict__ w1t,
    const float* __restrict__ fc1, u16* __restrict__ fc1c,
    const float* __restrict__ fc2, u16* __restrict__ fc2t,
    const float* __restrict__ fc1b, const float* __restrict__ fc2b,
    float* __restrict__ bfused)
{
    __shared__ float t[32][33];
    __shared__ float red[4][64];
    int b = blockIdx.x;
    if (b >= 1472) {            // fused bias: b[n] = fc1_b @ fc2[:,n] + fc2_b[n], split-k x4
        int nl = (b - 1472) * 64 + (threadIdx.x & 63);
        int kq = threadIdx.x >> 6;            // k-quarter 0..3
        float s = 0.f;
        if (nl < Vv) {
            #pragma unroll 8
            for (int k = 0; k < 64; k++) {
                int kk = kq * 64 + k;
                s += fc1b[kk] * fc2[(size_t)kk * Vv + nl];
            }
        }
        red[kq][threadIdx.x & 63] = s;
        __syncthreads();
        if (kq == 0 && nl < Vv)
            bfused[nl] = red[0][nl & 63] + red[1][nl & 63] + red[2][nl & 63]
                       + red[3][nl & 63] + fc2b[nl];
        return;
    }
    if (b >= 384 && b < 448) {              // fc1 straight cast (natural [j][ko] layout)
        int i = (b - 384) * 1024 + threadIdx.x * 4;
        float4 v = *(const float4*)(fc1 + i);
        __align__(8) u16 o[4] = {f2bf(v.x), f2bf(v.y), f2bf(v.z), f2bf(v.w)};
        *(uint2*)&fc1c[i] = *(const uint2*)o;
        return;
    }
    const float* in; u16* out; int K, N, bx, by;
    if (b < 384) { in = w1;  out = w1t;  K = 512; N = 768; bx = b % 24;  by = b / 24; }
    else { b -= 448; in = fc2; out = fc2t; K = 256; N = Vv; bx = b % 128; by = b / 128; }
    int n0 = bx * 32, k0 = by * 32;
    int c = threadIdx.x & 31, r = threadIdx.x >> 5;   // 8 rows per phase
    int n = n0 + c;
    #pragma unroll
    for (int i = 0; i < 32; i += 8)
        t[r + i][c] = (n < N) ? in[(size_t)(k0 + r + i) * N + n] : 0.f;
    __syncthreads();
    #pragma unroll
    for (int i = 0; i < 32; i += 8)
        out[(size_t)(n0 + r + i) * K + k0 + c] = f2bf(t[c][r + i]);
}

// ---- fused gather + GEMM1 + GRU cell (h0=0): tile 64 batch x 64 h-cols x 3 gates ----
// Single-barrier pipelined: per iter {sync; issue B(t+1)+stage A(t+1)+load a(t+2); compute t}.
__global__ __launch_bounds__(256) void gru_fused(
    const int* __restrict__ tokens, const float* __restrict__ features,
    const float* __restrict__ emb,  const u16* __restrict__ BT,   // w1t [768 x 512] bf16
    const float* __restrict__ gb,   // gru_bias [2 x 768] f32
    u16* __restrict__ h,            // [B x 256] bf16 (ws)
    float* __restrict__ state)      // [B x 256] f32 (output 1)
{
    __shared__ __align__(16) u16 As[2][64 * 32];
    __shared__ __align__(16) u16 Bs[2][3][64 * 32];
    __shared__ int tok[64];

    int tid = threadIdx.x;
    // chunked XCD swizzle: 4 n-tiles of one m-tile stay on one XCD (features L2 reuse)
    int id  = blockIdx.y * gridDim.x + blockIdx.x;
    int sid = (id & 7) * 64 + (id >> 3);
    int m0  = (sid >> 2) * 64;
    int n0  = (sid & 3) * 64;
    if (tid < 64) tok[tid] = tokens[m0 + tid];

    int wid = tid >> 6, lane = tid & 63, quad = lane >> 4, l16 = lane & 15;
    int wm = wid * 16;             // wave owns 16 rows x 64 cols x 3 gates

    f32x4 acc[3][4] = {};

    int r  = tid >> 2;             // 0..63 row
    int kc = (tid & 3) * 8;        // k-chunk within 32
    const u16* bg = BT + (size_t)(n0 + r) * INd + kc;
    const float* fsrc = features + (size_t)(m0 + r) * Ee + kc;

    // prologue: B(0) -> Bs[0]; convert A(0) -> As[0]; preload a-regs for k=32
    #pragma unroll
    for (int g = 0; g < 3; g++)
        gload16(bg + (size_t)g * 256 * INd, &Bs[0][g][tid * 8]);
    float4 a = *(const float4*)fsrc;            // k=0 (< Ee)
    float4 c = *(const float4*)(fsrc + 4);
    {
        u16 o[8] = {f2bf(a.x), f2bf(a.y), f2bf(a.z), f2bf(a.w),
                    f2bf(c.x), f2bf(c.y), f2bf(c.z), f2bf(c.w)};
        *(uint4*)&As[0][tid * 8] = *(const uint4*)o;
    }
    a = *(const float4*)(fsrc + 32);            // k=32 (< Ee)
    c = *(const float4*)(fsrc + 36);

    int cur = 0;
    for (int k0 = 0; k0 < INd; k0 += 32) {
        __syncthreads();   // drains B(k0)/a-regs; publishes As/Bs[cur] and tok[]
        int k1 = k0 + 32;
        if (k1 < INd) {
            #pragma unroll
            for (int g = 0; g < 3; g++)
                gload16(bg + (size_t)g * 256 * INd + k1, &Bs[cur ^ 1][g][tid * 8]);
            u16 o[8] = {f2bf(a.x), f2bf(a.y), f2bf(a.z), f2bf(a.w),
                        f2bf(c.x), f2bf(c.y), f2bf(c.z), f2bf(c.w)};
            *(uint4*)&As[cur ^ 1][tid * 8] = *(const uint4*)o;
            int k2 = k0 + 64;
            if (k2 < INd) {
                const float* src = (k2 < Ee) ? (fsrc + k2)
                                 : (emb + (size_t)tok[r] * Ee + (k2 - Ee) + kc);
                a = *(const float4*)src;
                c = *(const float4*)(src + 4);
            }
        }
        bf16x8 af = *(const bf16x8*)&As[cur][(wm + l16) * 32 + quad * 8];
        #pragma unroll
        for (int g = 0; g < 3; g++)
            #pragma unroll
            for (int j = 0; j < 4; j++) {
                bf16x8 bfv = *(const bf16x8*)&Bs[cur][g][(j * 16 + l16) * 32 + quad * 8];
                acc[g][j] = __builtin_amdgcn_mfma_f32_16x16x32_bf16(af, bfv, acc[g][j], 0, 0, 0);
            }
        cur ^= 1;
    }

    // C/D layout: col = l16, row = quad*4 + r (verified)
    #pragma unroll
    for (int j = 0; j < 4; j++) {
        int jj = n0 + j * 16 + l16;
        float bz  = gb[jj]          + gb[G3 + jj];
        float br  = gb[Uu + jj]     + gb[G3 + Uu + jj];
        float b0n = gb[2 * Uu + jj];
        float b1n = gb[G3 + 2 * Uu + jj];
        #pragma unroll
        for (int rr = 0; rr < 4; rr++) {
            int b = m0 + wm + quad * 4 + rr;
            float z  = 1.f / (1.f + __expf(-(acc[0][j][rr] + bz)));
            float rg = 1.f / (1.f + __expf(-(acc[1][j][rr] + br)));
            float n  = tanhf(acc[2][j][rr] + b0n + rg * b1n);
            float hv = (1.f - z) * n;
            h[(size_t)b * Uu + jj] = f2bf(hv);
            state[(size_t)b * Uu + jj] = hv;
        }
    }
}

// ---- pipelined GEMM: C[M x N] = A[M x K](bf16) @ BT[Nb x K]^T(bf16) (+ bias) ----
// 256 thr / 4 waves, BK=32, double-buffered LDS, one barrier per K-step:
// {sync (drains stage t); stage t+1 into other buffer; ds_read+MFMA tile t}.
template<int BMt, int BNt, bool OUT_BF16, bool HAS_BIAS>
__global__ __launch_bounds__(256) void gemm_bt(
    const u16* __restrict__ A, const u16* __restrict__ BT,
    const float* __restrict__ bias, void* __restrict__ Cout,
    int N, int K)   // N = real out cols (epilogue-guarded); grid covers padded cols
{
    constexpr int NW_N  = (BNt == 128) ? 2 : 1;   // waves along n
    constexpr int NW_M  = 4 / NW_N;               // waves along m
    constexpr int WROWS = BMt / NW_M;             // rows per wave
    constexpr int MI    = WROWS / 16;

    __shared__ __align__(16) u16 As[2][BMt * 32];
    __shared__ __align__(16) u16 Bs[2][BNt * 32];

    int tid = threadIdx.x;
    int m0   = blockIdx.y * BMt;
    int n0   = blockIdx.x * BNt;
    int wid  = tid >> 6, lane = tid & 63, quad = lane >> 4, l16 = lane & 15;
    int wm   = (wid / NW_N) * WROWS;
    int wn   = (wid % NW_N) * 64;

    f32x4 acc[MI][4] = {};

    const u16* ag = A  + (size_t)(m0 + (tid >> 2)) * K + (tid & 3) * 8;
    const u16* bg = BT + (size_t)(n0 + (tid >> 2)) * K + (tid & 3) * 8;

    // prologue: stage k=0 into buffer 0
    #pragma unroll
    for (int s = 0; s < BMt / 64; s++)
        gload16(ag + (size_t)s * 64 * K, &As[0][tid * 8 + s * 64 * 32]);
    #pragma unroll
    for (int s = 0; s < BNt / 64; s++)
        gload16(bg + (size_t)s * 64 * K, &Bs[0][tid * 8 + s * 64 * 32]);

    int cur = 0;
    for (int k0 = 0; k0 < K; k0 += 32) {
        __syncthreads();            // drains stage(cur) + last iter's ds_reads
        int k1 = k0 + 32;
        if (k1 < K) {
            #pragma unroll
            for (int s = 0; s < BMt / 64; s++)
                gload16(ag + (size_t)s * 64 * K + k1, &As[cur ^ 1][tid * 8 + s * 64 * 32]);
            #pragma unroll
            for (int s = 0; s < BNt / 64; s++)
                gload16(bg + (size_t)s * 64 * K + k1, &Bs[cur ^ 1][tid * 8 + s * 64 * 32]);
        }

        bf16x8 af[MI], bf[4];
        #pragma unroll
        for (int i = 0; i < MI; i++)
            af[i] = *(const bf16x8*)&As[cur][(wm + i * 16 + l16) * 32 + quad * 8];
        #pragma unroll
        for (int j = 0; j < 4; j++)
            bf[j] = *(const bf16x8*)&Bs[cur][(wn + j * 16 + l16) * 32 + quad * 8];
        #pragma unroll
        for (int i = 0; i < MI; i++)
            #pragma unroll
            for (int j = 0; j < 4; j++)
                acc[i][j] = __builtin_amdgcn_mfma_f32_16x16x32_bf16(af[i], bf[j], acc[i][j], 0, 0, 0);
        cur ^= 1;
    }

    // C/D layout: col = l16, row = quad*4 + r (verified)
    #pragma unroll
    for (int i = 0; i < MI; i++)
    #pragma unroll
    for (int j = 0; j < 4; j++) {
        int gn = n0 + wn + j * 16 + l16;
        if (gn >= N) continue;
        float bv = HAS_BIAS ? bias[gn] : 0.f;
        #pragma unroll
        for (int r = 0; r < 4; r++) {
            int gm = m0 + wm + i * 16 + quad * 4 + r;
            float v = acc[i][j][r] + bv;
            if (OUT_BF16) ((u16*)Cout)[(size_t)gm * N + gn] = f2bf(v);
            else          ((float*)Cout)[(size_t)gm * N + gn] = v;
        }
    }
}

extern "C" void kernel_launch(void* const* d_in, const int* in_sizes, int n_in,
                              void* d_out, int out_size, void* d_ws, size_t ws_size,
                              hipStream_t stream)
{
    const int*   tokens   = (const int*)d_in[0];
    const float* features = (const float*)d_in[1];
    // d_in[2] = hidden (unused: reference GRU starts from zeros)
    const float* emb      = (const float*)d_in[3];
    const float* w1       = (const float*)d_in[4];   // [512 x 768]
    // d_in[5] = gru_rkernel (unused: h0 = 0)
    const float* gbias    = (const float*)d_in[6];   // [2 x 768]
    const float* fc1w     = (const float*)d_in[7];   // [256 x 256]
    const float* fc1b     = (const float*)d_in[8];
    const float* fc2w     = (const float*)d_in[9];   // [256 x 4000]
    const float* fc2b     = (const float*)d_in[10];

    float* logits = (float*)d_out;                       // [8192 x 4000] f32
    float* state  = logits + (size_t)Bsz * Vv;           // [8192 x 256] f32

    char* ws = (char*)d_ws;
    u16*   w1t    = (u16*)(ws);                 //   786,432 B : [768 x 512]
    u16*   fc1c   = (u16*)(ws +   786432);      //   131,072 B : [256 x 256] (cast, no transpose)
    u16*   fc2t   = (u16*)(ws +   917504);      // 2,097,152 B : [4096 x 256] (pad zeroed)
    u16*   Wt     = (u16*)(ws +  3014656);      // 2,097,152 B : [4096 x 256] = (fc1@fc2)^T
    u16*   h      = (u16*)(ws +  5111808);      // 4,194,304 B : [8192 x 256]
    float* bfused = (float*)(ws + 9306112);     //    16,000 B : [4000]
    // total ws use: 9,322,112 B

    // prep: transposes (f32 -> bf16, k-contiguous), fc1 cast, fused bias (split-k x4)
    prep_all<<<dim3(1536), 256, 0, stream>>>(w1, w1t, fc1w, fc1c, fc2w, fc2t,
                                             fc1b, fc2b, bfused);

    // Wt[nl][j] = sum_ko fc2t[nl][ko] * fc1[j][ko]  -> collapsed fc1+fc2 weight, bf16
    gemm_bt<64, 64, true, false><<<dim3(Uu / 64, Vpad / 64), 256, 0, stream>>>(
        fc2t, fc1c, nullptr, (void*)Wt, Uu, Uu);

    // fused gather + gx-GEMM + GRU -> h (bf16) and state (f32 out)
    gru_fused<<<dim3(Uu / 64, Bsz / 64), 256, 0, stream>>>(
        tokens, features, emb, w1t, gbias, h, state);

    // logits = h @ W + bfused (f32 out), padded col grid, guarded epilogue
    gemm_bt<128, 128, false, true><<<dim3(Vpad / 128, Bsz / 128), 256, 0, stream>>>(
        h, Wt, bfused, (void*)logits, Vv, Uu);
}

// Round 4
// 211.373 us; speedup vs baseline: 1.1177x; 1.0410x over previous
//
#include <hip/hip_runtime.h>
#include <stdint.h>

typedef unsigned short u16;
typedef __attribute__((ext_vector_type(8))) short bf16x8;
typedef __attribute__((ext_vector_type(4))) float f32x4;

// ---- constants (problem shape) ----
#define Bsz   8192
#define Vv    4000
#define Vpad  4096
#define Ee    256
#define Uu    256
#define INd   512
#define G3    768   // 3*U

__device__ __forceinline__ u16 f2bf(float f) {
    union { float f; uint32_t i; } v; v.f = f;
    uint32_t x = v.i;
    return (u16)((x + 0x7fffu + ((x >> 16) & 1u)) >> 16);  // RNE
}

// async global->LDS, 16B per lane (dest = wave-uniform base + lane*16)
__device__ __forceinline__ void gload16(const u16* g, u16* l) {
    __builtin_amdgcn_global_load_lds(
        (const __attribute__((address_space(1))) unsigned int*)g,
        (__attribute__((address_space(3))) unsigned int*)l, 16, 0, 0);
}

// ---- prep: w1 transpose only (f32 [512][768] -> bf16 [768][512]) ----
__global__ __launch_bounds__(256) void prep_w1(
    const float* __restrict__ w1, u16* __restrict__ w1t)
{
    __shared__ float t[32][33];
    int b  = blockIdx.x;           // 384 blocks: 24 x 16 tiles of 32x32
    int bx = b % 24, by = b / 24;
    int n0 = bx * 32, k0 = by * 32;
    int c = threadIdx.x & 31, r = threadIdx.x >> 5;   // 8 rows per phase
    #pragma unroll
    for (int i = 0; i < 32; i += 8)
        t[r + i][c] = w1[(size_t)(k0 + r + i) * 768 + n0 + c];
    __syncthreads();
    #pragma unroll
    for (int i = 0; i < 32; i += 8)
        w1t[(size_t)(n0 + r + i) * 512 + k0 + c] = f2bf(t[c][r + i]);
}

// ---- mid: merged {gru (512 blk) | Wt-GEMM w/ inline transpose (256 blk) | bias (64 blk)} ----
// All branches are block-uniform; LDS manually overlaid (max user = gru's 33,024 B).
__global__ __launch_bounds__(256) void mid_all(
    const int* __restrict__ tokens, const float* __restrict__ features,
    const float* __restrict__ emb,  const u16* __restrict__ BT,    // w1t [768 x 512] bf16
    const float* __restrict__ gb,   // gru_bias [2 x 768] f32
    u16* __restrict__ h,            // [B x 256] bf16 (ws)
    float* __restrict__ state,      // [B x 256] f32 (output 1)
    const float* __restrict__ fc2,  // [256 x 4000] f32
    const float* __restrict__ fc1,  // [256 x 256] f32
    const float* __restrict__ fc1b, const float* __restrict__ fc2b,
    u16* __restrict__ Wt,           // [4096 x 256] bf16 = (fc1@fc2)^T, pad rows zero
    float* __restrict__ bfused)     // [4000] f32
{
    __shared__ __align__(16) char smem[33024];
    int b   = blockIdx.x;
    int tid = threadIdx.x;

    if (b < 512) {
        // ================= GRU: fused gather + gx-GEMM + cell (h0=0) =================
        u16* AsP = (u16*)smem;            // [2][64*32]
        u16* BsP = AsP + 4096;            // [2][3][64*32]
        int* tok = (int*)(smem + 32768);  // [64]

        // chunked XCD swizzle: 4 n-tiles of one m-tile stay on one XCD
        int sid = (b & 7) * 64 + (b >> 3);
        int m0  = (sid >> 2) * 64;
        int n0  = (sid & 3) * 64;
        if (tid < 64) tok[tid] = tokens[m0 + tid];

        int wid = tid >> 6, lane = tid & 63, quad = lane >> 4, l16 = lane & 15;
        int wm = wid * 16;             // wave owns 16 rows x 64 cols x 3 gates

        f32x4 acc[3][4] = {};

        int r  = tid >> 2;             // 0..63 row
        int kc = (tid & 3) * 8;        // k-chunk within 32
        const u16* bg = BT + (size_t)(n0 + r) * INd + kc;
        const float* fsrc = features + (size_t)(m0 + r) * Ee + kc;

        // prologue: B(0) -> buf0; convert A(0) -> buf0; preload a-regs for k=32
        #pragma unroll
        for (int g = 0; g < 3; g++)
            gload16(bg + (size_t)g * 256 * INd, &BsP[g * 2048 + tid * 8]);
        float4 a = *(const float4*)fsrc;            // k=0 (< Ee)
        float4 c = *(const float4*)(fsrc + 4);
        {
            u16 o[8] = {f2bf(a.x), f2bf(a.y), f2bf(a.z), f2bf(a.w),
                        f2bf(c.x), f2bf(c.y), f2bf(c.z), f2bf(c.w)};
            *(uint4*)&AsP[tid * 8] = *(const uint4*)o;
        }
        a = *(const float4*)(fsrc + 32);            // k=32 (< Ee)
        c = *(const float4*)(fsrc + 36);

        int cur = 0;
        for (int k0 = 0; k0 < INd; k0 += 32) {
            __syncthreads();   // drains B(k0)/a-regs; publishes buf[cur] and tok[]
            int k1 = k0 + 32;
            if (k1 < INd) {
                #pragma unroll
                for (int g = 0; g < 3; g++)
                    gload16(bg + (size_t)g * 256 * INd + k1,
                            &BsP[(cur ^ 1) * 6144 + g * 2048 + tid * 8]);
                u16 o[8] = {f2bf(a.x), f2bf(a.y), f2bf(a.z), f2bf(a.w),
                            f2bf(c.x), f2bf(c.y), f2bf(c.z), f2bf(c.w)};
                *(uint4*)&AsP[(cur ^ 1) * 2048 + tid * 8] = *(const uint4*)o;
                int k2 = k0 + 64;
                if (k2 < INd) {
                    const float* src = (k2 < Ee) ? (fsrc + k2)
                                     : (emb + (size_t)tok[r] * Ee + (k2 - Ee) + kc);
                    a = *(const float4*)src;
                    c = *(const float4*)(src + 4);
                }
            }
            bf16x8 af = *(const bf16x8*)&AsP[cur * 2048 + (wm + l16) * 32 + quad * 8];
            #pragma unroll
            for (int g = 0; g < 3; g++)
                #pragma unroll
                for (int j = 0; j < 4; j++) {
                    bf16x8 bfv = *(const bf16x8*)&BsP[cur * 6144 + g * 2048
                                                     + (j * 16 + l16) * 32 + quad * 8];
                    acc[g][j] = __builtin_amdgcn_mfma_f32_16x16x32_bf16(af, bfv, acc[g][j], 0, 0, 0);
                }
            cur ^= 1;
        }

        // C/D layout: col = l16, row = quad*4 + r (verified)
        #pragma unroll
        for (int j = 0; j < 4; j++) {
            int jj = n0 + j * 16 + l16;
            float bz  = gb[jj]          + gb[G3 + jj];
            float br  = gb[Uu + jj]     + gb[G3 + Uu + jj];
            float b0n = gb[2 * Uu + jj];
            float b1n = gb[G3 + 2 * Uu + jj];
            #pragma unroll
            for (int rr = 0; rr < 4; rr++) {
                int bb = m0 + wm + quad * 4 + rr;
                float z  = 1.f / (1.f + __expf(-(acc[0][j][rr] + bz)));
                float rg = 1.f / (1.f + __expf(-(acc[1][j][rr] + br)));
                float n  = tanhf(acc[2][j][rr] + b0n + rg * b1n);
                float hv = (1.f - z) * n;
                h[(size_t)bb * Uu + jj] = f2bf(hv);
                state[(size_t)bb * Uu + jj] = hv;
            }
        }
    } else if (b < 768) {
        // ===== Wt-GEMM: Wt[n][i] = sum_j fc2[j][n] * fc1[i][j], inline transpose =====
        // 64x64 tile, single-buffer LDS, 2 barriers/step, loads(t+1) hidden under compute(t)
        int wb = b - 512;                 // 256 blocks: 4 i-tiles x 64 n-tiles
        int i0 = (wb & 3) * 64;
        int n0 = (wb >> 2) * 64;          // vocab row tile (padded grid)
        u16* Aw = (u16*)smem;             // [64*32] fc2^T tile, bf16
        u16* Bw = Aw + 2048;              // [64*32] fc1 rows tile, bf16

        int wid = tid >> 6, lane = tid & 63, quad = lane >> 4, l16 = lane & 15;
        int wm  = wid * 16;
        int nn  = tid >> 2, jc = (tid & 3) * 8;
        int nv  = n0 + nn;
        bool nok = nv < Vv;

        f32x4 acc[4] = {};
        float a8[8]; float4 bA, bB;

        // LOAD(t): A = fc2 column-gather (transposed), B = fc1 rows (straight)
        #define WT_LOAD(J0)                                                        \
            do {                                                                   \
                _Pragma("unroll")                                                  \
                for (int p = 0; p < 8; p++)                                        \
                    a8[p] = nok ? fc2[(size_t)((J0) + jc + p) * Vv + nv] : 0.f;    \
                bA = *(const float4*)&fc1[(size_t)(i0 + nn) * 256 + (J0) + jc];    \
                bB = *(const float4*)&fc1[(size_t)(i0 + nn) * 256 + (J0) + jc + 4];\
            } while (0)

        WT_LOAD(0);
        for (int t = 0; t < 8; t++) {
            __syncthreads();              // previous compute done reading LDS
            {
                u16 oa[8] = {f2bf(a8[0]), f2bf(a8[1]), f2bf(a8[2]), f2bf(a8[3]),
                             f2bf(a8[4]), f2bf(a8[5]), f2bf(a8[6]), f2bf(a8[7])};
                *(uint4*)&Aw[tid * 8] = *(const uint4*)oa;
                u16 ob[8] = {f2bf(bA.x), f2bf(bA.y), f2bf(bA.z), f2bf(bA.w),
                             f2bf(bB.x), f2bf(bB.y), f2bf(bB.z), f2bf(bB.w)};
                *(uint4*)&Bw[tid * 8] = *(const uint4*)ob;
            }
            __syncthreads();              // tile published
            if (t < 7) WT_LOAD((t + 1) * 32);   // latency hidden under MFMA below
            bf16x8 af = *(const bf16x8*)&Aw[(wm + l16) * 32 + quad * 8];
            #pragma unroll
            for (int j = 0; j < 4; j++) {
                bf16x8 bfv = *(const bf16x8*)&Bw[(j * 16 + l16) * 32 + quad * 8];
                acc[j] = __builtin_amdgcn_mfma_f32_16x16x32_bf16(af, bfv, acc[j], 0, 0, 0);
            }
        }
        #undef WT_LOAD

        // D: row(quad*4+rr) = vocab n, col(j*16+l16) = i   (pad rows -> 0, A was zeroed)
        #pragma unroll
        for (int j = 0; j < 4; j++)
            #pragma unroll
            for (int rr = 0; rr < 4; rr++)
                Wt[(size_t)(n0 + wm + quad * 4 + rr) * 256 + i0 + j * 16 + l16]
                    = f2bf(acc[j][rr]);
    } else {
        // ===== fused bias: bfused[n] = fc1_b @ fc2[:,n] + fc2_b[n], split-k x4 =====
        float* red = (float*)smem;        // [4][64]
        int bb = b - 768;                 // 64 blocks
        int nl = bb * 64 + (tid & 63);
        int kq = tid >> 6;
        float s = 0.f;
        if (nl < Vv) {
            #pragma unroll 8
            for (int k = 0; k < 64; k++) {
                int kk = kq * 64 + k;
                s += fc1b[kk] * fc2[(size_t)kk * Vv + nl];
            }
        }
        red[kq * 64 + (tid & 63)] = s;
        __syncthreads();
        if (kq == 0 && nl < Vv)
            bfused[nl] = red[nl & 63] + red[64 + (nl & 63)] + red[128 + (nl & 63)]
                       + red[192 + (nl & 63)] + fc2b[nl];
    }
}

// ---- pipelined GEMM: C[M x N] = A[M x K](bf16) @ BT[Nb x K]^T(bf16) (+ bias) ----
// 256 thr / 4 waves, BK=32, double-buffered LDS, one barrier per K-step.
template<int BMt, int BNt, bool OUT_BF16, bool HAS_BIAS>
__global__ __launch_bounds__(256) void gemm_bt(
    const u16* __restrict__ A, const u16* __restrict__ BT,
    const float* __restrict__ bias, void* __restrict__ Cout,
    int N, int K)   // N = real out cols (epilogue-guarded); grid covers padded cols
{
    constexpr int NW_N  = (BNt == 128) ? 2 : 1;   // waves along n
    constexpr int NW_M  = 4 / NW_N;               // waves along m
    constexpr int WROWS = BMt / NW_M;             // rows per wave
    constexpr int MI    = WROWS / 16;

    __shared__ __align__(16) u16 As[2][BMt * 32];
    __shared__ __align__(16) u16 Bs[2][BNt * 32];

    int tid = threadIdx.x;
    int m0   = blockIdx.y * BMt;
    int n0   = blockIdx.x * BNt;
    int wid  = tid >> 6, lane = tid & 63, quad = lane >> 4, l16 = lane & 15;
    int wm   = (wid / NW_N) * WROWS;
    int wn   = (wid % NW_N) * 64;

    f32x4 acc[MI][4] = {};

    const u16* ag = A  + (size_t)(m0 + (tid >> 2)) * K + (tid & 3) * 8;
    const u16* bg = BT + (size_t)(n0 + (tid >> 2)) * K + (tid & 3) * 8;

    // prologue: stage k=0 into buffer 0
    #pragma unroll
    for (int s = 0; s < BMt / 64; s++)
        gload16(ag + (size_t)s * 64 * K, &As[0][tid * 8 + s * 64 * 32]);
    #pragma unroll
    for (int s = 0; s < BNt / 64; s++)
        gload16(bg + (size_t)s * 64 * K, &Bs[0][tid * 8 + s * 64 * 32]);

    int cur = 0;
    for (int k0 = 0; k0 < K; k0 += 32) {
        __syncthreads();            // drains stage(cur) + last iter's ds_reads
        int k1 = k0 + 32;
        if (k1 < K) {
            #pragma unroll
            for (int s = 0; s < BMt / 64; s++)
                gload16(ag + (size_t)s * 64 * K + k1, &As[cur ^ 1][tid * 8 + s * 64 * 32]);
            #pragma unroll
            for (int s = 0; s < BNt / 64; s++)
                gload16(bg + (size_t)s * 64 * K + k1, &Bs[cur ^ 1][tid * 8 + s * 64 * 32]);
        }

        bf16x8 af[MI], bf[4];
        #pragma unroll
        for (int i = 0; i < MI; i++)
            af[i] = *(const bf16x8*)&As[cur][(wm + i * 16 + l16) * 32 + quad * 8];
        #pragma unroll
        for (int j = 0; j < 4; j++)
            bf[j] = *(const bf16x8*)&Bs[cur][(wn + j * 16 + l16) * 32 + quad * 8];
        #pragma unroll
        for (int i = 0; i < MI; i++)
            #pragma unroll
            for (int j = 0; j < 4; j++)
                acc[i][j] = __builtin_amdgcn_mfma_f32_16x16x32_bf16(af[i], bf[j], acc[i][j], 0, 0, 0);
        cur ^= 1;
    }

    // C/D layout: col = l16, row = quad*4 + r (verified)
    #pragma unroll
    for (int i = 0; i < MI; i++)
    #pragma unroll
    for (int j = 0; j < 4; j++) {
        int gn = n0 + wn + j * 16 + l16;
        if (gn >= N) continue;
        float bv = HAS_BIAS ? bias[gn] : 0.f;
        #pragma unroll
        for (int r = 0; r < 4; r++) {
            int gm = m0 + wm + i * 16 + quad * 4 + r;
            float v = acc[i][j][r] + bv;
            if (OUT_BF16) ((u16*)Cout)[(size_t)gm * N + gn] = f2bf(v);
            else          ((float*)Cout)[(size_t)gm * N + gn] = v;
        }
    }
}

extern "C" void kernel_launch(void* const* d_in, const int* in_sizes, int n_in,
                              void* d_out, int out_size, void* d_ws, size_t ws_size,
                              hipStream_t stream)
{
    const int*   tokens   = (const int*)d_in[0];
    const float* features = (const float*)d_in[1];
    // d_in[2] = hidden (unused: reference GRU starts from zeros)
    const float* emb      = (const float*)d_in[3];
    const float* w1       = (const float*)d_in[4];   // [512 x 768]
    // d_in[5] = gru_rkernel (unused: h0 = 0)
    const float* gbias    = (const float*)d_in[6];   // [2 x 768]
    const float* fc1w     = (const float*)d_in[7];   // [256 x 256]
    const float* fc1b     = (const float*)d_in[8];
    const float* fc2w     = (const float*)d_in[9];   // [256 x 4000]
    const float* fc2b     = (const float*)d_in[10];

    float* logits = (float*)d_out;                       // [8192 x 4000] f32
    float* state  = logits + (size_t)Bsz * Vv;           // [8192 x 256] f32

    char* ws = (char*)d_ws;
    u16*   w1t    = (u16*)(ws);                 //   786,432 B : [768 x 512]
    u16*   Wt     = (u16*)(ws +   786432);      // 2,097,152 B : [4096 x 256] = (fc1@fc2)^T
    u16*   h      = (u16*)(ws +  2883584);      // 4,194,304 B : [8192 x 256]
    float* bfused = (float*)(ws +  7077888);    //    16,000 B : [4000]
    // total ws use: 7,093,888 B

    // 1) w1 transpose (f32 -> bf16, k-contiguous) — only remaining prep
    prep_w1<<<dim3(384), 256, 0, stream>>>(w1, w1t);

    // 2) merged: gru (512) | Wt-GEMM w/ inline fc2-transpose + fc1-cast (256) | bias (64)
    mid_all<<<dim3(832), 256, 0, stream>>>(
        tokens, features, emb, w1t, gbias, h, state,
        fc2w, fc1w, fc1b, fc2b, Wt, bfused);

    // 3) logits = h @ W + bfused (f32 out), padded col grid, guarded epilogue
    gemm_bt<128, 128, false, true><<<dim3(Vpad / 128, Bsz / 128), 256, 0, stream>>>(
        h, Wt, bfused, (void*)logits, Vv, Uu);
}